// Round 4
// baseline (60.919 us; speedup 1.0000x reference)
//
#include <hip/hip_runtime.h>
#include <math.h>

#define CB 16          // class_bit
#define ALPHA 0.1f
#define LOG2E 1.4426950408889634f

typedef __bf16 bf16x8 __attribute__((ext_vector_type(8)));
typedef float  f32x16 __attribute__((ext_vector_type(16)));

__device__ inline float block_reduce_256(float v, float* red) {
    #pragma unroll
    for (int off = 32; off > 0; off >>= 1) v += __shfl_down(v, off, 64);
    int lane = threadIdx.x & 63;
    int wid  = threadIdx.x >> 6;
    if (lane == 0) red[wid] = v;
    __syncthreads();
    float s = 0.f;
    if (threadIdx.x == 0) {
        int nw = blockDim.x >> 6;
        for (int w = 0; w < nw; ++w) s += red[w];
    }
    return s;
}

// Fused prep:
//  blocks [0, nub):        u_[b,c,d] = sum_k u[b,k]*w_D[c,k,d]
//                          -> u_f32 [b][c][d], u_bf [c][b][d] (scaled by log2e),
//                             quantization partials
//  blocks [nub, nub+n_cls): v[c,d] = sum_k w_D[c,k,d]*yu[c,k],
//                           w[c,d] = sum_k w_D[c,k,d]*su[k]
//                           (yu = y^T u, su = column-sum of u; independent of u_f32)
__global__ __launch_bounds__(256) void prep_kernel(
        const float* __restrict__ u, const float* __restrict__ y,
        const float* __restrict__ w_D,
        float* __restrict__ u_f32, __bf16* __restrict__ u_bf,
        float* __restrict__ quant_partials,
        float* __restrict__ vvec, float* __restrict__ wvec,
        int n_bs, int bit, int n_cls, int nub) {
    __shared__ float red[4];
    __shared__ float yus[4][64];
    __shared__ float sus[4][64];
    if ((int)blockIdx.x < nub) {
        int idx = blockIdx.x * 256 + threadIdx.x;
        int total = n_bs * n_cls * CB;
        float q = 0.f;
        if (idx < total) {
            int d = idx & (CB - 1);
            int c = (idx / CB) % n_cls;
            int b = idx / (CB * n_cls);
            const float* __restrict__ ur = u + (size_t)b * bit;
            const float* __restrict__ w  = w_D + (size_t)c * bit * CB + d;
            float s = 0.f;
            for (int k = 0; k < bit; ++k) s = fmaf(ur[k], w[k * CB], s);
            u_f32[idx] = s;
            u_bf[((size_t)c * n_bs + b) * CB + d] = (__bf16)(s * LOG2E);
            float sgn = (s > 0.f) ? 1.f : ((s < 0.f) ? -1.f : 0.f);
            float dd = s - sgn;
            q = dd * dd;
        }
        float bs = block_reduce_256(q, red);
        if (threadIdx.x == 0) quant_partials[blockIdx.x] = bs;
    } else {
        const int c  = blockIdx.x - nub;
        const int kk = threadIdx.x & 63;       // k index (bit <= 64)
        const int sl = threadIdx.x >> 6;       // 4 b-slices
        float yv = 0.f, sv = 0.f;
        if (kk < bit) {
            const int bpp = n_bs >> 2;
            for (int b = sl * bpp; b < (sl + 1) * bpp; ++b) {
                float uv = u[(size_t)b * bit + kk];
                sv += uv;
                yv = fmaf(y[(size_t)b * n_cls + c], uv, yv);
            }
        }
        yus[sl][kk] = yv; sus[sl][kk] = sv;
        __syncthreads();
        if (sl == 0 && kk < bit) {
            yus[0][kk] = yus[0][kk] + yus[1][kk] + yus[2][kk] + yus[3][kk];
            sus[0][kk] = sus[0][kk] + sus[1][kk] + sus[2][kk] + sus[3][kk];
        }
        __syncthreads();
        if (threadIdx.x < CB) {
            const int d = threadIdx.x;
            const float* __restrict__ wdc = w_D + (size_t)c * bit * CB + d;
            float v = 0.f, w = 0.f;
            for (int k = 0; k < bit; ++k) {
                float wv = wdc[k * CB];
                v = fmaf(yus[0][k], wv, v);
                w = fmaf(sus[0][k], wv, w);
            }
            vvec[(size_t)c * CB + d] = v;
            wvec[(size_t)c * CB + d] = w;
        }
    }
}

// One block = 64-row t-tile x 4 classes (one class per wave, 2 MFMA row-tiles).
// No inv buffer: per-block LDS patch list from ind (distinct rows).
__global__ __launch_bounds__(256) void loss_main_mfma(
        const float* __restrict__ y, const float* __restrict__ U,
        const float* __restrict__ Yb, const float* __restrict__ u_f32,
        const __bf16* __restrict__ u_bf,
        const float* __restrict__ vvec, const float* __restrict__ wvec,
        const int* __restrict__ ind, float* __restrict__ partials, int nblk,
        int n_bs, int n_cls, int n_train) {
    __shared__ float red[4 * 4];
    __shared__ int plist[64];
    __shared__ int pn;
    const int tid  = threadIdx.x;
    const int lane = tid & 63;
    const int wid  = tid >> 6;
    const int c    = blockIdx.x * 4 + wid;
    const int t0   = blockIdx.y * 64;
    const int r    = lane & 31;
    const int h    = lane >> 5;
    const int row0 = t0 + r;
    const int row1 = t0 + 32 + r;

    if (tid == 0) pn = 0;

    // unconditional parallel loads (common case); clamp pad rows
    const int rc0 = (row0 < n_train) ? row0 : (n_train - 1);
    const int rc1 = (row1 < n_train) ? row1 : (n_train - 1);
    const float* __restrict__ ar0 = U + ((size_t)rc0 * n_cls + c) * CB + h * 8;
    const float* __restrict__ ar1 = U + ((size_t)rc1 * n_cls + c) * CB + h * 8;
    float4 a00 = *(const float4*)(ar0);
    float4 a01 = *(const float4*)(ar0 + 4);
    float4 a10 = *(const float4*)(ar1);
    float4 a11 = *(const float4*)(ar1 + 4);
    float Yv0 = Yb[(size_t)rc0 * n_cls + c];
    float Yv1 = Yb[(size_t)rc1 * n_cls + c];

    __syncthreads();                       // pn = 0 visible
    if (tid < n_bs) {
        int t = ind[tid];
        int rl = t - t0;
        if (rl >= 0 && rl < 64) {
            int s = atomicAdd(&pn, 1);
            plist[s] = (rl << 16) | tid;
        }
    }
    __syncthreads();                       // patch list complete

    const int np = pn;
    for (int i = 0; i < np; ++i) {
        int p  = plist[i];
        int rl = p >> 16;
        int b  = p & 0xFFFF;
        if ((rl & 31) == r) {
            const float* __restrict__ src =
                u_f32 + ((size_t)b * n_cls + c) * CB + h * 8;
            float4 p0 = *(const float4*)(src);
            float4 p1 = *(const float4*)(src + 4);
            float  py = y[(size_t)b * n_cls + c];
            if (rl < 32) { a00 = p0; a01 = p1; Yv0 = py; }
            else         { a10 = p0; a11 = p1; Yv1 = py; }
        }
    }
    if (row0 >= n_train) {
        a00 = make_float4(0.f,0.f,0.f,0.f); a01 = a00; Yv0 = 0.f;
    }
    if (row1 >= n_train) {
        a10 = make_float4(0.f,0.f,0.f,0.f); a11 = a10; Yv1 = 0.f;
    }

    // side dots: sum_b s*ip -> Yv*(U_row.v), sum_b ip -> U_row.w
    const float* __restrict__ vp = vvec + (size_t)c * CB + h * 8;
    const float* __restrict__ wp = wvec + (size_t)c * CB + h * 8;
    float sv0 = a00.x*vp[0] + a00.y*vp[1] + a00.z*vp[2] + a00.w*vp[3]
              + a01.x*vp[4] + a01.y*vp[5] + a01.z*vp[6] + a01.w*vp[7];
    float sw0 = a00.x*wp[0] + a00.y*wp[1] + a00.z*wp[2] + a00.w*wp[3]
              + a01.x*wp[4] + a01.y*wp[5] + a01.z*wp[6] + a01.w*wp[7];
    float sv1 = a10.x*vp[0] + a10.y*vp[1] + a10.z*vp[2] + a10.w*vp[3]
              + a11.x*vp[4] + a11.y*vp[5] + a11.z*vp[6] + a11.w*vp[7];
    float sw1 = a10.x*wp[0] + a10.y*wp[1] + a10.z*wp[2] + a10.w*wp[3]
              + a11.x*wp[4] + a11.y*wp[5] + a11.z*wp[6] + a11.w*wp[7];
    float sideS = Yv0 * sv0 + Yv1 * sv1;
    float sideW = sw0 + sw1;

    bf16x8 A[2];
    A[0][0] = (__bf16)a00.x; A[0][1] = (__bf16)a00.y;
    A[0][2] = (__bf16)a00.z; A[0][3] = (__bf16)a00.w;
    A[0][4] = (__bf16)a01.x; A[0][5] = (__bf16)a01.y;
    A[0][6] = (__bf16)a01.z; A[0][7] = (__bf16)a01.w;
    A[1][0] = (__bf16)a10.x; A[1][1] = (__bf16)a10.y;
    A[1][2] = (__bf16)a10.z; A[1][3] = (__bf16)a10.w;
    A[1][4] = (__bf16)a11.x; A[1][5] = (__bf16)a11.y;
    A[1][6] = (__bf16)a11.z; A[1][7] = (__bf16)a11.w;

    const __bf16* __restrict__ ub = u_bf + (size_t)c * n_bs * CB;
    bf16x8 B[4];
    #pragma unroll
    for (int bt = 0; bt < 4; ++bt)
        B[bt] = *(const bf16x8*)(ub + (size_t)(bt * 32 + r) * CB + h * 8);

    float accL = 0.f;   // sum log2(1 + 2^(-|ip'|))  (pad rows add exactly 1)
    float accA = 0.f;   // sum |ip'|
    f32x16 zc = {};
    #pragma unroll
    for (int at = 0; at < 2; ++at) {
        #pragma unroll
        for (int bt = 0; bt < 4; ++bt) {
            f32x16 D = __builtin_amdgcn_mfma_f32_32x32x16_bf16(
                           A[at], B[bt], zc, 0, 0, 0);
            float a[16];
            #pragma unroll
            for (int j = 0; j < 16; ++j) {
                float ipa = fabsf(D[j]);
                a[j] = 1.0f + __builtin_amdgcn_exp2f(-ipa);
                accA += ipa;
            }
            #pragma unroll
            for (int s = 1; s < 16; s <<= 1)
                #pragma unroll
                for (int j = 0; j < 16; j += 2 * s) a[j] *= a[j + s];
            accL += __builtin_amdgcn_logf(a[0]);   // v_log_f32 = log2
        }
    }

    #pragma unroll
    for (int off = 32; off > 0; off >>= 1) {
        accL  += __shfl_down(accL,  off, 64);
        accA  += __shfl_down(accA,  off, 64);
        sideS += __shfl_down(sideS, off, 64);
        sideW += __shfl_down(sideW, off, 64);
    }
    if (lane == 0) {
        red[wid * 4 + 0] = accL;
        red[wid * 4 + 1] = accA;
        red[wid * 4 + 2] = sideS;
        red[wid * 4 + 3] = sideW;
    }
    __syncthreads();
    if (tid < 4) {
        float s = red[0 * 4 + tid] + red[1 * 4 + tid]
                + red[2 * 4 + tid] + red[3 * 4 + tid];
        int bid = blockIdx.y * gridDim.x + blockIdx.x;
        partials[(size_t)tid * nblk + bid] = s;
    }
}

__global__ __launch_bounds__(256) void finalize_kernel(
        const float* __restrict__ partials, int nblk,
        const float* __restrict__ quant_partials, int n_quant,
        float* __restrict__ out, double n_pad,
        double like_scale, double quant_scale) {
    double sL = 0, sA = 0, sS = 0, sW = 0, sQ = 0;
    for (int i = threadIdx.x; i < nblk; i += 256) {
        sL += (double)partials[0 * nblk + i];
        sA += (double)partials[1 * nblk + i];
        sS += (double)partials[2 * nblk + i];
        sW += (double)partials[3 * nblk + i];
    }
    for (int i = threadIdx.x; i < n_quant; i += 256) sQ += (double)quant_partials[i];
    #pragma unroll
    for (int off = 32; off > 0; off >>= 1) {
        sL += __shfl_down(sL, off, 64);
        sA += __shfl_down(sA, off, 64);
        sS += __shfl_down(sS, off, 64);
        sW += __shfl_down(sW, off, 64);
        sQ += __shfl_down(sQ, off, 64);
    }
    __shared__ double red[4][5];
    int lane = threadIdx.x & 63, wid = threadIdx.x >> 6;
    if (lane == 0) {
        red[wid][0] = sL; red[wid][1] = sA; red[wid][2] = sS;
        red[wid][3] = sW; red[wid][4] = sQ;
    }
    __syncthreads();
    if (threadIdx.x == 0) {
        double L = 0, Aa = 0, S = 0, W = 0, Q = 0;
        for (int w = 0; w < 4; ++w) {
            L += red[w][0]; Aa += red[w][1]; S += red[w][2];
            W += red[w][3]; Q  += red[w][4];
        }
        const double ln2 = 0.6931471805599453;
        double like = ln2 * (L - n_pad + 0.5 * Aa) + 0.5 * W - S;
        out[0] = (float)(like * like_scale + Q * quant_scale);
    }
}

extern "C" void kernel_launch(void* const* d_in, const int* in_sizes, int n_in,
                              void* d_out, int out_size, void* d_ws, size_t ws_size,
                              hipStream_t stream) {
    const float* u   = (const float*)d_in[0];
    const float* y   = (const float*)d_in[1];
    const int*   ind = (const int*)d_in[2];
    const float* U   = (const float*)d_in[3];
    const float* Yb  = (const float*)d_in[4];
    const float* w_D = (const float*)d_in[5];

    const int n_bs    = in_sizes[2];             // 128
    const int bit     = in_sizes[0] / n_bs;      // 48
    const int n_cls   = in_sizes[1] / n_bs;      // 100
    const int n_train = in_sizes[4] / n_cls;     // 10000

    const int totalU = n_bs * n_cls * CB;
    const int nub    = (totalU + 255) / 256;     // 800
    const int ntile  = (n_train + 63) / 64;      // 157
    const int gx     = (n_cls + 3) / 4;          // 25
    const int nblk   = ntile * gx;

    char* ws = (char*)d_ws;
    size_t off = 0;
    float* u_f32 = (float*)(ws + off);          off += (size_t)totalU * 4;
    __bf16* u_bf = (__bf16*)(ws + off);         off += (size_t)totalU * 2;
    off = (off + 15) & ~(size_t)15;
    float* vvec = (float*)(ws + off);           off += (size_t)n_cls * CB * 4;
    float* wvec = (float*)(ws + off);           off += (size_t)n_cls * CB * 4;
    float* quant_partials = (float*)(ws + off); off += (size_t)nub * 4;
    off = (off + 15) & ~(size_t)15;
    float* partials = (float*)(ws + off);       off += (size_t)nblk * 4 * 4;

    prep_kernel<<<nub + n_cls, 256, 0, stream>>>(
        u, y, w_D, u_f32, u_bf, quant_partials, vvec, wvec,
        n_bs, bit, n_cls, nub);
    loss_main_mfma<<<dim3(gx, ntile), 256, 0, stream>>>(
        y, U, Yb, u_f32, u_bf, vvec, wvec, ind, partials, nblk,
        n_bs, n_cls, n_train);

    const double n_pad = (double)((long long)(ntile * 64 - n_train) *
                                  (long long)n_bs * (long long)n_cls);
    const double like_scale  = 1.0 / ((double)n_bs * n_train * n_cls);
    const double quant_scale = (double)ALPHA / (double)totalU;
    finalize_kernel<<<1, 256, 0, stream>>>(partials, nblk, quant_partials, nub,
                                           (float*)d_out, n_pad,
                                           like_scale, quant_scale);
}

// Round 5
// 56.235 us; speedup vs baseline: 1.0833x; 1.0833x over previous
//
#include <hip/hip_runtime.h>
#include <math.h>

#define CB 16          // class_bit
#define ALPHA 0.1f
#define LOG2E 1.4426950408889634f

typedef __bf16 bf16x8 __attribute__((ext_vector_type(8)));
typedef float  f32x16 __attribute__((ext_vector_type(16)));

__device__ inline float block_reduce_256(float v, float* red) {
    #pragma unroll
    for (int off = 32; off > 0; off >>= 1) v += __shfl_down(v, off, 64);
    int lane = threadIdx.x & 63;
    int wid  = threadIdx.x >> 6;
    if (lane == 0) red[wid] = v;
    __syncthreads();
    float s = 0.f;
    if (threadIdx.x == 0) {
        int nw = blockDim.x >> 6;
        for (int w = 0; w < nw; ++w) s += red[w];
    }
    return s;
}

// Fused prep:
//  blocks [0, nub):        u_[b,c,d] = sum_k u[b,k]*w_D[c,k,d]
//                          -> u_f32 [b][c][d], u_bf [c][b][d] (scaled by log2e),
//                             quantization partials
//  blocks [nub, nub+n_cls): v[c,d] = sum_k w_D[c,k,d]*yu[c,k],
//                           w[c,d] = sum_k w_D[c,k,d]*su[k]
__global__ __launch_bounds__(256) void prep_kernel(
        const float* __restrict__ u, const float* __restrict__ y,
        const float* __restrict__ w_D,
        float* __restrict__ u_f32, __bf16* __restrict__ u_bf,
        float* __restrict__ quant_partials,
        float* __restrict__ vvec, float* __restrict__ wvec,
        int n_bs, int bit, int n_cls, int nub) {
    __shared__ float red[4];
    __shared__ float yus[4][64];
    __shared__ float sus[4][64];
    if ((int)blockIdx.x < nub) {
        int idx = blockIdx.x * 256 + threadIdx.x;
        int total = n_bs * n_cls * CB;
        float q = 0.f;
        if (idx < total) {
            int d = idx & (CB - 1);
            int c = (idx / CB) % n_cls;
            int b = idx / (CB * n_cls);
            const float* __restrict__ ur = u + (size_t)b * bit;
            const float* __restrict__ w  = w_D + (size_t)c * bit * CB + d;
            float s = 0.f;
            for (int k = 0; k < bit; ++k) s = fmaf(ur[k], w[k * CB], s);
            u_f32[idx] = s;
            u_bf[((size_t)c * n_bs + b) * CB + d] = (__bf16)(s * LOG2E);
            float sgn = (s > 0.f) ? 1.f : ((s < 0.f) ? -1.f : 0.f);
            float dd = s - sgn;
            q = dd * dd;
        }
        float bs = block_reduce_256(q, red);
        if (threadIdx.x == 0) quant_partials[blockIdx.x] = bs;
    } else {
        const int c  = blockIdx.x - nub;
        const int kk = threadIdx.x & 63;       // k index (bit <= 64)
        const int sl = threadIdx.x >> 6;       // 4 b-slices
        float yv = 0.f, sv = 0.f;
        if (kk < bit) {
            const int bpp = n_bs >> 2;
            for (int b = sl * bpp; b < (sl + 1) * bpp; ++b) {
                float uv = u[(size_t)b * bit + kk];
                sv += uv;
                yv = fmaf(y[(size_t)b * n_cls + c], uv, yv);
            }
        }
        yus[sl][kk] = yv; sus[sl][kk] = sv;
        __syncthreads();
        if (sl == 0 && kk < bit) {
            yus[0][kk] = yus[0][kk] + yus[1][kk] + yus[2][kk] + yus[3][kk];
            sus[0][kk] = sus[0][kk] + sus[1][kk] + sus[2][kk] + sus[3][kk];
        }
        __syncthreads();
        if (threadIdx.x < CB) {
            const int d = threadIdx.x;
            const float* __restrict__ wdc = w_D + (size_t)c * bit * CB + d;
            float v = 0.f, w = 0.f;
            for (int k = 0; k < bit; ++k) {
                float wv = wdc[k * CB];
                v = fmaf(yus[0][k], wv, v);
                w = fmaf(sus[0][k], wv, w);
            }
            vvec[(size_t)c * CB + d] = v;
            wvec[(size_t)c * CB + d] = w;
        }
    }
}

// One block = 32-row t-tile x 4 classes (one class per wave, 4 MFMAs/wave).
// No inv buffer: per-block LDS patch list from ind (distinct rows).
// Minimal live state per wave (1 A-frag, 1 D-chain) -> high occupancy for TLP.
__global__ __launch_bounds__(256, 4) void loss_main_mfma(
        const float* __restrict__ y, const float* __restrict__ U,
        const float* __restrict__ Yb, const float* __restrict__ u_f32,
        const __bf16* __restrict__ u_bf,
        const float* __restrict__ vvec, const float* __restrict__ wvec,
        const int* __restrict__ ind, float* __restrict__ partials, int nblk,
        int n_bs, int n_cls, int n_train) {
    __shared__ float red[4 * 4];
    __shared__ int plist[32];
    __shared__ int pn;
    const int tid  = threadIdx.x;
    const int lane = tid & 63;
    const int wid  = tid >> 6;
    const int c    = blockIdx.x * 4 + wid;
    const int t0   = blockIdx.y * 32;
    const int r    = lane & 31;
    const int h    = lane >> 5;
    const int row  = t0 + r;

    if (tid == 0) pn = 0;

    // unconditional parallel loads (common case); clamp pad rows
    const int rc = (row < n_train) ? row : (n_train - 1);
    const float* __restrict__ ar = U + ((size_t)rc * n_cls + c) * CB + h * 8;
    float4 a0 = *(const float4*)(ar);
    float4 a1 = *(const float4*)(ar + 4);
    float Yv = Yb[(size_t)rc * n_cls + c];

    __syncthreads();                       // pn = 0 visible
    if (tid < n_bs) {
        int t = ind[tid];
        int rl = t - t0;
        if (rl >= 0 && rl < 32) {
            int s = atomicAdd(&pn, 1);
            plist[s] = (rl << 16) | tid;
        }
    }
    __syncthreads();                       // patch list complete

    const int np = pn;
    for (int i = 0; i < np; ++i) {
        int p  = plist[i];
        int rl = p >> 16;
        int b  = p & 0xFFFF;
        if (rl == r) {
            const float* __restrict__ src =
                u_f32 + ((size_t)b * n_cls + c) * CB + h * 8;
            a0 = *(const float4*)(src);
            a1 = *(const float4*)(src + 4);
            Yv = y[(size_t)b * n_cls + c];
        }
    }
    if (row >= n_train) {
        a0 = make_float4(0.f, 0.f, 0.f, 0.f); a1 = a0; Yv = 0.f;
    }

    // side dots: sum_b s*ip -> Yv*(U_row.v), sum_b ip -> U_row.w
    const float* __restrict__ vp = vvec + (size_t)c * CB + h * 8;
    const float* __restrict__ wp = wvec + (size_t)c * CB + h * 8;
    float sv = a0.x*vp[0] + a0.y*vp[1] + a0.z*vp[2] + a0.w*vp[3]
             + a1.x*vp[4] + a1.y*vp[5] + a1.z*vp[6] + a1.w*vp[7];
    float sw = a0.x*wp[0] + a0.y*wp[1] + a0.z*wp[2] + a0.w*wp[3]
             + a1.x*wp[4] + a1.y*wp[5] + a1.z*wp[6] + a1.w*wp[7];
    float sideS = Yv * sv;
    float sideW = sw;

    bf16x8 A;
    A[0] = (__bf16)a0.x; A[1] = (__bf16)a0.y;
    A[2] = (__bf16)a0.z; A[3] = (__bf16)a0.w;
    A[4] = (__bf16)a1.x; A[5] = (__bf16)a1.y;
    A[6] = (__bf16)a1.z; A[7] = (__bf16)a1.w;

    const __bf16* __restrict__ ub = u_bf + (size_t)c * n_bs * CB;
    bf16x8 B[4];
    #pragma unroll
    for (int bt = 0; bt < 4; ++bt)
        B[bt] = *(const bf16x8*)(ub + (size_t)(bt * 32 + r) * CB + h * 8);

    float accL = 0.f;   // sum log2(1 + 2^(-|ip'|))  (pad rows add exactly 1)
    float accA = 0.f;   // sum |ip'|
    f32x16 zc = {};
    #pragma unroll
    for (int bt = 0; bt < 4; ++bt) {
        f32x16 D = __builtin_amdgcn_mfma_f32_32x32x16_bf16(A, B[bt], zc, 0, 0, 0);
        float a[16];
        #pragma unroll
        for (int j = 0; j < 16; ++j) {
            float ipa = fabsf(D[j]);
            a[j] = 1.0f + __builtin_amdgcn_exp2f(-ipa);  // neg-abs = src modifier
            accA += ipa;
        }
        // product tree of 16: a in (1,2] -> prod in (1,65536], exact-safe
        #pragma unroll
        for (int s = 1; s < 16; s <<= 1)
            #pragma unroll
            for (int j = 0; j < 16; j += 2 * s) a[j] *= a[j + s];
        accL += __builtin_amdgcn_logf(a[0]);             // v_log_f32 = log2
    }

    #pragma unroll
    for (int off = 32; off > 0; off >>= 1) {
        accL  += __shfl_down(accL,  off, 64);
        accA  += __shfl_down(accA,  off, 64);
        sideS += __shfl_down(sideS, off, 64);
        sideW += __shfl_down(sideW, off, 64);
    }
    if (lane == 0) {
        red[wid * 4 + 0] = accL;
        red[wid * 4 + 1] = accA;
        red[wid * 4 + 2] = sideS;
        red[wid * 4 + 3] = sideW;
    }
    __syncthreads();
    if (tid < 4) {
        float s = red[0 * 4 + tid] + red[1 * 4 + tid]
                + red[2 * 4 + tid] + red[3 * 4 + tid];
        int bid = blockIdx.y * gridDim.x + blockIdx.x;
        partials[(size_t)tid * nblk + bid] = s;
    }
}

__global__ __launch_bounds__(256) void finalize_kernel(
        const float* __restrict__ partials, int nblk,
        const float* __restrict__ quant_partials, int n_quant,
        float* __restrict__ out, double n_pad,
        double like_scale, double quant_scale) {
    double sL = 0, sA = 0, sS = 0, sW = 0, sQ = 0;
    for (int i = threadIdx.x; i < nblk; i += 256) {
        sL += (double)partials[0 * nblk + i];
        sA += (double)partials[1 * nblk + i];
        sS += (double)partials[2 * nblk + i];
        sW += (double)partials[3 * nblk + i];
    }
    for (int i = threadIdx.x; i < n_quant; i += 256) sQ += (double)quant_partials[i];
    #pragma unroll
    for (int off = 32; off > 0; off >>= 1) {
        sL += __shfl_down(sL, off, 64);
        sA += __shfl_down(sA, off, 64);
        sS += __shfl_down(sS, off, 64);
        sW += __shfl_down(sW, off, 64);
        sQ += __shfl_down(sQ, off, 64);
    }
    __shared__ double red[4][5];
    int lane = threadIdx.x & 63, wid = threadIdx.x >> 6;
    if (lane == 0) {
        red[wid][0] = sL; red[wid][1] = sA; red[wid][2] = sS;
        red[wid][3] = sW; red[wid][4] = sQ;
    }
    __syncthreads();
    if (threadIdx.x == 0) {
        double L = 0, Aa = 0, S = 0, W = 0, Q = 0;
        for (int w = 0; w < 4; ++w) {
            L += red[w][0]; Aa += red[w][1]; S += red[w][2];
            W += red[w][3]; Q  += red[w][4];
        }
        const double ln2 = 0.6931471805599453;
        // Aa = log2e * sum|ip|  ->  0.5*sum|ip| = 0.5*ln2*Aa
        double like = ln2 * (L - n_pad + 0.5 * Aa) + 0.5 * W - S;
        out[0] = (float)(like * like_scale + Q * quant_scale);
    }
}

extern "C" void kernel_launch(void* const* d_in, const int* in_sizes, int n_in,
                              void* d_out, int out_size, void* d_ws, size_t ws_size,
                              hipStream_t stream) {
    const float* u   = (const float*)d_in[0];
    const float* y   = (const float*)d_in[1];
    const int*   ind = (const int*)d_in[2];
    const float* U   = (const float*)d_in[3];
    const float* Yb  = (const float*)d_in[4];
    const float* w_D = (const float*)d_in[5];

    const int n_bs    = in_sizes[2];             // 128
    const int bit     = in_sizes[0] / n_bs;      // 48
    const int n_cls   = in_sizes[1] / n_bs;      // 100
    const int n_train = in_sizes[4] / n_cls;     // 10000

    const int totalU = n_bs * n_cls * CB;
    const int nub    = (totalU + 255) / 256;     // 800
    const int ntile  = (n_train + 31) / 32;      // 313
    const int gx     = (n_cls + 3) / 4;          // 25
    const int nblk   = ntile * gx;

    char* ws = (char*)d_ws;
    size_t off = 0;
    float* u_f32 = (float*)(ws + off);          off += (size_t)totalU * 4;
    __bf16* u_bf = (__bf16*)(ws + off);         off += (size_t)totalU * 2;
    off = (off + 15) & ~(size_t)15;
    float* vvec = (float*)(ws + off);           off += (size_t)n_cls * CB * 4;
    float* wvec = (float*)(ws + off);           off += (size_t)n_cls * CB * 4;
    float* quant_partials = (float*)(ws + off); off += (size_t)nub * 4;
    off = (off + 15) & ~(size_t)15;
    float* partials = (float*)(ws + off);       off += (size_t)nblk * 4 * 4;

    prep_kernel<<<nub + n_cls, 256, 0, stream>>>(
        u, y, w_D, u_f32, u_bf, quant_partials, vvec, wvec,
        n_bs, bit, n_cls, nub);
    loss_main_mfma<<<dim3(gx, ntile), 256, 0, stream>>>(
        y, U, Yb, u_f32, u_bf, vvec, wvec, ind, partials, nblk,
        n_bs, n_cls, n_train);

    const double n_pad = (double)((long long)(ntile * 32 - n_train) *
                                  (long long)n_bs * (long long)n_cls);
    const double like_scale  = 1.0 / ((double)n_bs * n_train * n_cls);
    const double quant_scale = (double)ALPHA / (double)totalU;
    finalize_kernel<<<1, 256, 0, stream>>>(partials, nblk, quant_partials, nub,
                                           (float*)d_out, n_pad,
                                           like_scale, quant_scale);
}